// Round 9
// baseline (67.632 us; speedup 1.0000x reference)
//
#include <hip/hip_runtime.h>
#include <hip/hip_bf16.h>
#include <hip/hip_cooperative_groups.h>
#include <float.h>

namespace cg = cooperative_groups;

// Problem constants: B=16, M=4096.
#define NB 16
#define MPTS 4096
#define NPRED (NB * MPTS)        // 65536
#define NT 128                   // gt tiles (32 pts) per batch
#define CT 64                    // tiles per LDS chunk (64 KB)
#define BLK 256                  // 4 waves
#define F 2                      // B-frags (32 preds) per wave
#define PREDS_PER_BLK (BLK / 64 * F * 32)   // 256
#define PGRP (MPTS / PREDS_PER_BLK)         // 16
#define NBLOCKS (NB * PGRP)                 // 256 = 1 block/CU (co-resident)

typedef _Float16 half8 __attribute__((ext_vector_type(8)));
typedef float f32x16 __attribute__((ext_vector_type(16)));

__device__ inline void split16(float x, _Float16& hi, _Float16& lo) {
    hi = (_Float16)x;
    lo = (_Float16)(x - (float)hi);
}

// Single cooperative kernel. Block = (batch b, 256-pred group).
// S[gt][pred] = gn - 2 p.g via mfma_f32_32x32x16_f16, hi/lo split (R7 layout):
//  A kh0: [hux,huy,huz,hux,huy,huz,lux,luy]  A kh1: [luz,gnh,gnl,0,0,0,0,0]
//  B kh0: [hpx,hpy,hpz,lpx,lpy,lpz,hpx,hpy]  B kh1: [hpz,1,1,0,0,0,0,0]
// GT side staged locally (transform+pack in VALU) in 2 chunks of 64 tiles.
// Per-pred min completes in-block; one grid.sync; block 0 writes the mean.
__global__ __launch_bounds__(BLK) void adds_all(
    const float* __restrict__ pred_R, const float* __restrict__ pred_t,
    const float* __restrict__ gt_R,   const float* __restrict__ gt_t,
    const float* __restrict__ mp,     float* __restrict__ partial,
    float* __restrict__ out)
{
    __shared__ half8 aT[CT * 64];        // 64 KB
    __shared__ float wsum[4];

    const int bid = blockIdx.x;
    const int b   = bid >> 4;
    const int pg  = bid & 15;
    const int tid = threadIdx.x;
    const int ln  = tid & 63;
    const int wv  = tid >> 6;
    const int kh  = ln >> 5;

    // ---- gt transform constants ----
    float gR[9];
#pragma unroll
    for (int i = 0; i < 9; ++i) gR[i] = gt_R[b * 9 + i];
    const float gtx = gt_t[b * 3 + 0];
    const float gty = gt_t[b * 3 + 1];
    const float gtz = gt_t[b * 3 + 2];

    // ---- B fragments (this wave's F*32 preds), before first sync ----
    float pR[9];
#pragma unroll
    for (int i = 0; i < 9; ++i) pR[i] = pred_R[b * 9 + i];
    const float ptx = pred_t[b * 3 + 0];
    const float pty = pred_t[b * 3 + 1];
    const float ptz = pred_t[b * 3 + 2];

    half8 bf[F];
    float pn[F];
#pragma unroll
    for (int f = 0; f < F; ++f) {
        const int predl = pg * PREDS_PER_BLK + wv * (F * 32) + f * 32 + (ln & 31);
        const float mx = mp[predl * 3 + 0];
        const float my = mp[predl * 3 + 1];
        const float mz = mp[predl * 3 + 2];
        const float px = fmaf(pR[0], mx, fmaf(pR[1], my, fmaf(pR[2], mz, ptx)));
        const float py = fmaf(pR[3], mx, fmaf(pR[4], my, fmaf(pR[5], mz, pty)));
        const float pz = fmaf(pR[6], mx, fmaf(pR[7], my, fmaf(pR[8], mz, ptz)));
        pn[f] = fmaf(px, px, fmaf(py, py, pz * pz));
        _Float16 hpx, lpx, hpy, lpy, hpz, lpz;
        split16(px, hpx, lpx);
        split16(py, hpy, lpy);
        split16(pz, hpz, lpz);
        half8 v;
        if (kh == 0) {
            v[0] = hpx; v[1] = hpy; v[2] = hpz;
            v[3] = lpx; v[4] = lpy; v[5] = lpz;
            v[6] = hpx; v[7] = hpy;
        } else {
            v[0] = hpz; v[1] = (_Float16)1.0f; v[2] = (_Float16)1.0f;
            v[3] = (_Float16)0.0f; v[4] = (_Float16)0.0f; v[5] = (_Float16)0.0f;
            v[6] = (_Float16)0.0f; v[7] = (_Float16)0.0f;
        }
        bf[f] = v;
    }

    f32x16 zc;
#pragma unroll
    for (int i = 0; i < 16; ++i) zc[i] = 0.0f;

    float best[F][8];
#pragma unroll
    for (int f = 0; f < F; ++f)
#pragma unroll
        for (int j = 0; j < 8; ++j) best[f][j] = FLT_MAX;

    // ---- 2 chunks: stage 64 tiles locally, then MFMA over them ----
    for (int c = 0; c < 2; ++c) {
        // stage: 2048 points -> 4096 half8 entries (8 points/thread)
#pragma unroll
        for (int j = 0; j < 8; ++j) {
            const int pidx = j * BLK + tid;            // 0..2047 in chunk
            const int n    = c * (CT * 32) + pidx;     // gt index in batch
            const float mx = mp[n * 3 + 0];
            const float my = mp[n * 3 + 1];
            const float mz = mp[n * 3 + 2];
            const float gx = fmaf(gR[0], mx, fmaf(gR[1], my, fmaf(gR[2], mz, gtx)));
            const float gy = fmaf(gR[3], mx, fmaf(gR[4], my, fmaf(gR[5], mz, gty)));
            const float gz = fmaf(gR[6], mx, fmaf(gR[7], my, fmaf(gR[8], mz, gtz)));
            const float gn = fmaf(gx, gx, fmaf(gy, gy, gz * gz));
            const float ux = -2.0f * gx, uy = -2.0f * gy, uz = -2.0f * gz;
            _Float16 hux, lux, huy, luy, huz, luz, gnh, gnl;
            split16(ux, hux, lux);
            split16(uy, huy, luy);
            split16(uz, huz, luz);
            split16(gn, gnh, gnl);
            half8 k0, k1;
            k0[0] = hux; k0[1] = huy; k0[2] = huz;
            k0[3] = hux; k0[4] = huy; k0[5] = huz;
            k0[6] = lux; k0[7] = luy;
            k1[0] = luz; k1[1] = gnh; k1[2] = gnl;
            k1[3] = (_Float16)0.0f; k1[4] = (_Float16)0.0f; k1[5] = (_Float16)0.0f;
            k1[6] = (_Float16)0.0f; k1[7] = (_Float16)0.0f;
            const int tl = pidx >> 5, r = pidx & 31;
            aT[tl * 64 + r]      = k0;
            aT[tl * 64 + 32 + r] = k1;
        }
        __syncthreads();

#pragma unroll 4
        for (int t = 0; t < CT; ++t) {
            const half8 a = aT[t * 64 + ln];
            const f32x16 d0 = __builtin_amdgcn_mfma_f32_32x32x16_f16(a, bf[0], zc, 0, 0, 0);
            const f32x16 d1 = __builtin_amdgcn_mfma_f32_32x32x16_f16(a, bf[1], zc, 0, 0, 0);
#pragma unroll
            for (int j = 0; j < 8; ++j) {
                best[0][j] = fminf(best[0][j], fminf(d0[2 * j], d0[2 * j + 1]));  // v_min3
                best[1][j] = fminf(best[1][j], fminf(d1[2 * j], d1[2 * j + 1]));
            }
        }
        __syncthreads();    // before restaging over the same buffer
    }

    // ---- epilogue: fold, merge k-halves, sqrt, block sum ----
    float s = 0.0f;
#pragma unroll
    for (int f = 0; f < F; ++f) {
        float r = fminf(fminf(fminf(best[f][0], best[f][1]), fminf(best[f][2], best[f][3])),
                        fminf(fminf(best[f][4], best[f][5]), fminf(best[f][6], best[f][7])));
        r = fminf(r, __shfl_xor(r, 32, 64));
        s += sqrtf(fmaxf(pn[f] + r, 0.0f));
    }
#pragma unroll
    for (int off = 32; off > 0; off >>= 1) s += __shfl_down(s, off, 64);
    if (ln == 0) wsum[wv] = s * 0.5f;      // lanes l and l+32 duplicate preds
    __syncthreads();
    if (tid == 0) partial[bid] = (wsum[0] + wsum[1]) + (wsum[2] + wsum[3]);

    cg::this_grid().sync();

    // ---- block 0: 256 partials -> mean ----
    if (bid == 0) {
        float v = partial[tid];
#pragma unroll
        for (int off = 32; off > 0; off >>= 1) v += __shfl_down(v, off, 64);
        if ((tid & 63) == 0) wsum[tid >> 6] = v;
        __syncthreads();
        if (tid == 0)
            out[0] = ((wsum[0] + wsum[1]) + (wsum[2] + wsum[3])) * (1.0f / (float)NPRED);
    }
}

extern "C" void kernel_launch(void* const* d_in, const int* in_sizes, int n_in,
                              void* d_out, int out_size, void* d_ws, size_t ws_size,
                              hipStream_t stream) {
    const float* pred_R = (const float*)d_in[0];
    const float* pred_t = (const float*)d_in[1];
    const float* gt_R   = (const float*)d_in[2];
    const float* gt_t   = (const float*)d_in[3];
    const float* mp     = (const float*)d_in[4];
    float* out = (float*)d_out;
    float* partial = (float*)d_ws;          // 256 floats

    void* args[] = {
        (void*)&pred_R, (void*)&pred_t, (void*)&gt_R, (void*)&gt_t,
        (void*)&mp, (void*)&partial, (void*)&out
    };
    hipLaunchCooperativeKernel((const void*)adds_all, dim3(NBLOCKS), dim3(BLK),
                               args, 0, stream);
}

// Round 10
// 22.379 us; speedup vs baseline: 3.0222x; 3.0222x over previous
//
#include <hip/hip_runtime.h>
#include <hip/hip_bf16.h>
#include <float.h>

// Problem constants: B=16, M=4096.
#define NB 16
#define MPTS 4096
#define NPRED (NB * MPTS)       // 65536 pred points
#define GTQ 4                   // gt quarters (one per block)
#define GTN 1024                // gt points per block
#define NT 32                   // MFMA tiles of 32 gt each
#define BLK 256                 // 4 waves
#define FRAGS 4                 // B-fragments (preds) per wave: 4*32 = 128
#define PREDS_PER_BLK 512       // 4 waves * 128
#define PGRP 8                  // pred groups per batch (4096/512)

typedef _Float16 half8 __attribute__((ext_vector_type(8)));
typedef float f32x16 __attribute__((ext_vector_type(16)));

// Split x into f16 hi + f16 lo (x ~= hi + lo).
__device__ inline void split16(float x, _Float16& hi, _Float16& lo) {
    hi = (_Float16)x;
    lo = (_Float16)(x - (float)hi);
}

// Main kernel (R7-proven): one block = (batch b, 512-pred group, gt quarter).
// S[gt][pred] = gn - 2 p.g via mfma_f32_32x32x16_f16 with hi/lo split K-slots:
//  A kh0: [hux,huy,huz,hux,huy,huz,lux,luy]  A kh1: [luz,gnh,gnl,0,0,0,0,0]
//  B kh0: [hpx,hpy,hpz,lpx,lpy,lpz,hpx,hpy]  B kh1: [hpz,1,1,0,0,0,0,0]
// Per tile: 1 ds_read_b128 + 4 MFMA + 32 v_min3. Block 0 also zeroes out[0]
// (kernel-boundary visibility) so the finish kernel can atomicAdd into it.
__global__ __launch_bounds__(BLK) void adds_mfma(
    const float* __restrict__ pred_R, const float* __restrict__ pred_t,
    const float* __restrict__ gt_R,   const float* __restrict__ gt_t,
    const float* __restrict__ mp,     float* __restrict__ pmin,
    float* __restrict__ out)
{
    __shared__ half8 aT[NT * 64];        // 32 KB, [tile][vlane] lane-read order

    const int bid = blockIdx.x;
    const int gtq = bid & (GTQ - 1);
    const int pg  = (bid >> 2) & (PGRP - 1);
    const int b   = bid >> 5;
    const int tid = threadIdx.x;
    const int ln  = tid & 63;
    const int wv  = tid >> 6;

    if (bid == 0 && tid == 0) out[0] = 0.0f;   // re-zero every call (replay-safe)

    // ---- stage A tiles (gt side) into LDS ----
    {
        float gR[9];
#pragma unroll
        for (int i = 0; i < 9; ++i) gR[i] = gt_R[b * 9 + i];
        const float gtx = gt_t[b * 3 + 0];
        const float gty = gt_t[b * 3 + 1];
        const float gtz = gt_t[b * 3 + 2];

#pragma unroll
        for (int w = 0; w < (NT * 64) / BLK; ++w) {   // 8 vlanes per thread
            const int v  = w * BLK + tid;             // 0..2047
            const int t  = v >> 6;
            const int vl = v & 63;
            const int n  = gtq * GTN + t * 32 + (vl & 31);
            const float mx = mp[n * 3 + 0];
            const float my = mp[n * 3 + 1];
            const float mz = mp[n * 3 + 2];
            const float gx = fmaf(gR[0], mx, fmaf(gR[1], my, fmaf(gR[2], mz, gtx)));
            const float gy = fmaf(gR[3], mx, fmaf(gR[4], my, fmaf(gR[5], mz, gty)));
            const float gz = fmaf(gR[6], mx, fmaf(gR[7], my, fmaf(gR[8], mz, gtz)));
            const float gn = fmaf(gx, gx, fmaf(gy, gy, gz * gz));
            const float ux = -2.0f * gx, uy = -2.0f * gy, uz = -2.0f * gz;
            _Float16 hux, lux, huy, luy, huz, luz, gnh, gnl;
            split16(ux, hux, lux);
            split16(uy, huy, luy);
            split16(uz, huz, luz);
            split16(gn, gnh, gnl);
            half8 pk;
            if ((vl >> 5) == 0) {        // k0..7
                pk[0] = hux; pk[1] = huy; pk[2] = huz;
                pk[3] = hux; pk[4] = huy; pk[5] = huz;
                pk[6] = lux; pk[7] = luy;
            } else {                      // k8..15
                pk[0] = luz; pk[1] = gnh; pk[2] = gnl;
                pk[3] = (_Float16)0.0f; pk[4] = (_Float16)0.0f;
                pk[5] = (_Float16)0.0f; pk[6] = (_Float16)0.0f;
                pk[7] = (_Float16)0.0f;
            }
            aT[v] = pk;
        }
    }

    // ---- B-fragments (pred side), constant across tiles ----
    float pR[9];
#pragma unroll
    for (int i = 0; i < 9; ++i) pR[i] = pred_R[b * 9 + i];
    const float ptx = pred_t[b * 3 + 0];
    const float pty = pred_t[b * 3 + 1];
    const float ptz = pred_t[b * 3 + 2];

    half8 bf[FRAGS];
    float pn[FRAGS];
    const int kh = ln >> 5;
#pragma unroll
    for (int f = 0; f < FRAGS; ++f) {
        const int predl = pg * PREDS_PER_BLK + wv * 128 + f * 32 + (ln & 31);
        const float mx = mp[predl * 3 + 0];
        const float my = mp[predl * 3 + 1];
        const float mz = mp[predl * 3 + 2];
        const float px = fmaf(pR[0], mx, fmaf(pR[1], my, fmaf(pR[2], mz, ptx)));
        const float py = fmaf(pR[3], mx, fmaf(pR[4], my, fmaf(pR[5], mz, pty)));
        const float pz = fmaf(pR[6], mx, fmaf(pR[7], my, fmaf(pR[8], mz, ptz)));
        pn[f] = fmaf(px, px, fmaf(py, py, pz * pz));
        _Float16 hpx, lpx, hpy, lpy, hpz, lpz;
        split16(px, hpx, lpx);
        split16(py, hpy, lpy);
        split16(pz, hpz, lpz);
        half8 v;
        if (kh == 0) {                    // k0..7
            v[0] = hpx; v[1] = hpy; v[2] = hpz;
            v[3] = lpx; v[4] = lpy; v[5] = lpz;
            v[6] = hpx; v[7] = hpy;
        } else {                          // k8..15
            v[0] = hpz; v[1] = (_Float16)1.0f; v[2] = (_Float16)1.0f;
            v[3] = (_Float16)0.0f; v[4] = (_Float16)0.0f;
            v[5] = (_Float16)0.0f; v[6] = (_Float16)0.0f;
            v[7] = (_Float16)0.0f;
        }
        bf[f] = v;
    }

    __syncthreads();

    // ---- MFMA loop over 32 gt tiles ----
    f32x16 zc;
#pragma unroll
    for (int i = 0; i < 16; ++i) zc[i] = 0.0f;

    float best[FRAGS][8];
#pragma unroll
    for (int f = 0; f < FRAGS; ++f)
#pragma unroll
        for (int j = 0; j < 8; ++j) best[f][j] = FLT_MAX;

    half8 a_cur = aT[ln];
    for (int t = 0; t < NT; ++t) {
        const half8 a_nxt = (t + 1 < NT) ? aT[(t + 1) * 64 + ln] : a_cur;
        const f32x16 d0 = __builtin_amdgcn_mfma_f32_32x32x16_f16(a_cur, bf[0], zc, 0, 0, 0);
        const f32x16 d1 = __builtin_amdgcn_mfma_f32_32x32x16_f16(a_cur, bf[1], zc, 0, 0, 0);
        const f32x16 d2 = __builtin_amdgcn_mfma_f32_32x32x16_f16(a_cur, bf[2], zc, 0, 0, 0);
        const f32x16 d3 = __builtin_amdgcn_mfma_f32_32x32x16_f16(a_cur, bf[3], zc, 0, 0, 0);
#pragma unroll
        for (int j = 0; j < 8; ++j) {
            best[0][j] = fminf(best[0][j], fminf(d0[2 * j], d0[2 * j + 1]));
            best[1][j] = fminf(best[1][j], fminf(d1[2 * j], d1[2 * j + 1]));
            best[2][j] = fminf(best[2][j], fminf(d2[2 * j], d2[2 * j + 1]));
            best[3][j] = fminf(best[3][j], fminf(d3[2 * j], d3[2 * j + 1]));
        }
        a_cur = a_nxt;
    }

    // ---- epilogue: fold 8 regs, merge lane halves, add pn, store ----
#pragma unroll
    for (int f = 0; f < FRAGS; ++f) {
        float r = fminf(fminf(fminf(best[f][0], best[f][1]), fminf(best[f][2], best[f][3])),
                        fminf(fminf(best[f][4], best[f][5]), fminf(best[f][6], best[f][7])));
        r = fminf(r, __shfl_xor(r, 32, 64));
        const float d2v = fmaxf(pn[f] + r, 0.0f);
        if (ln < 32) {
            const int predl = pg * PREDS_PER_BLK + wv * 128 + f * 32 + ln;
            pmin[gtq * NPRED + b * MPTS + predl] = d2v;
        }
    }
}

// Finish (single kernel): per pred point min over the 4 partials -> sqrt ->
// block sum -> one atomicAdd of the scaled partial into out[0].
// (out[0] zeroed by adds_mfma; f32 atomicAdd order-jitter ~1e-6 rel << 3e-2.)
__global__ __launch_bounds__(1024) void adds_finish(
    const float* __restrict__ pmin, float* __restrict__ out)
{
    __shared__ float wsum[16];
    const int tid = threadIdx.x;
    const int g = blockIdx.x * 1024 + tid;
    const float m0 = fminf(pmin[0 * NPRED + g], pmin[1 * NPRED + g]);
    const float m1 = fminf(pmin[2 * NPRED + g], pmin[3 * NPRED + g]);
    float s = sqrtf(fminf(m0, m1));
#pragma unroll
    for (int off = 32; off > 0; off >>= 1) s += __shfl_down(s, off, 64);
    if ((tid & 63) == 0) wsum[tid >> 6] = s;
    __syncthreads();
    if (tid == 0) {
        float t = 0.0f;
#pragma unroll
        for (int w = 0; w < 16; ++w) t += wsum[w];
        atomicAdd(out, t * (1.0f / (float)NPRED));
    }
}

extern "C" void kernel_launch(void* const* d_in, const int* in_sizes, int n_in,
                              void* d_out, int out_size, void* d_ws, size_t ws_size,
                              hipStream_t stream) {
    const float* pred_R = (const float*)d_in[0];
    const float* pred_t = (const float*)d_in[1];
    const float* gt_R   = (const float*)d_in[2];
    const float* gt_t   = (const float*)d_in[3];
    const float* mp     = (const float*)d_in[4];
    float* out = (float*)d_out;
    float* pmin = (float*)d_ws;                 // 4*64K*4 = 1 MB

    // grid: b(16) x pred-group(8) x gtq(4) = 512 blocks
    adds_mfma<<<dim3(NB * PGRP * GTQ), dim3(BLK), 0, stream>>>(
        pred_R, pred_t, gt_R, gt_t, mp, pmin, out);
    adds_finish<<<dim3(64), dim3(1024), 0, stream>>>(pmin, out);
}

// Round 11
// 20.078 us; speedup vs baseline: 3.3685x; 1.1146x over previous
//
#include <hip/hip_runtime.h>
#include <hip/hip_bf16.h>
#include <float.h>

// Problem constants: B=16, M=4096.
#define NB 16
#define MPTS 4096
#define NPRED (NB * MPTS)       // 65536 pred points
#define GTQ 8                   // gt eighths (one per block)
#define GTN 512                 // gt points per block
#define NT 16                   // MFMA tiles of 32 gt each per block
#define BLK 256                 // 4 waves
#define FRAGS 4                 // B-fragments (preds) per wave: 4*32 = 128
#define PREDS_PER_BLK 512       // 4 waves * 128
#define PGRP 8                  // pred groups per batch (4096/512)

typedef _Float16 half8 __attribute__((ext_vector_type(8)));
typedef float f32x16 __attribute__((ext_vector_type(16)));

// Split x into f16 hi + f16 lo (x ~= hi + lo).
__device__ inline void split16(float x, _Float16& hi, _Float16& lo) {
    hi = (_Float16)x;
    lo = (_Float16)(x - (float)hi);
}

// Main kernel: one block = (batch b, 512-pred group, gt eighth).
// S[gt][pred] = gn - 2 p.g via mfma_f32_32x32x16_f16 with hi/lo split K-slots:
//  A kh0: [hux,huy,huz,hux,huy,huz,lux,luy]  A kh1: [luz,gnh,gnl,0,0,0,0,0]
//  B kh0: [hpx,hpy,hpz,lpx,lpy,lpz,hpx,hpy]  B kh1: [hpz,1,1,0,0,0,0,0]
// 16 KB LDS + <=128 VGPR -> 4 blocks/CU (4 waves/SIMD). Per tile:
// 1 ds_read_b128 + 4 MFMA (2+2 groups) + 32 v_min3.
__global__ __launch_bounds__(BLK, 4) void adds_mfma(
    const float* __restrict__ pred_R, const float* __restrict__ pred_t,
    const float* __restrict__ gt_R,   const float* __restrict__ gt_t,
    const float* __restrict__ mp,     float* __restrict__ pmin,
    float* __restrict__ out)
{
    __shared__ half8 aT[NT * 64];        // 16 KB, [tile][vlane]

    const int bid = blockIdx.x;
    const int gtq = bid & (GTQ - 1);
    const int pg  = (bid >> 3) & (PGRP - 1);
    const int b   = bid >> 6;
    const int tid = threadIdx.x;
    const int ln  = tid & 63;
    const int wv  = tid >> 6;

    if (bid == 0 && tid == 0) out[0] = 0.0f;   // re-zero every call (replay-safe)

    // ---- stage A tiles: 512 points, one transform per point, 2 entries ----
    {
        float gR[9];
#pragma unroll
        for (int i = 0; i < 9; ++i) gR[i] = gt_R[b * 9 + i];
        const float gtx = gt_t[b * 3 + 0];
        const float gty = gt_t[b * 3 + 1];
        const float gtz = gt_t[b * 3 + 2];

#pragma unroll
        for (int j = 0; j < GTN / BLK; ++j) {         // 2 points per thread
            const int nl = j * BLK + tid;             // 0..511
            const int n  = gtq * GTN + nl;
            const float mx = mp[n * 3 + 0];
            const float my = mp[n * 3 + 1];
            const float mz = mp[n * 3 + 2];
            const float gx = fmaf(gR[0], mx, fmaf(gR[1], my, fmaf(gR[2], mz, gtx)));
            const float gy = fmaf(gR[3], mx, fmaf(gR[4], my, fmaf(gR[5], mz, gty)));
            const float gz = fmaf(gR[6], mx, fmaf(gR[7], my, fmaf(gR[8], mz, gtz)));
            const float gn = fmaf(gx, gx, fmaf(gy, gy, gz * gz));
            const float ux = -2.0f * gx, uy = -2.0f * gy, uz = -2.0f * gz;
            _Float16 hux, lux, huy, luy, huz, luz, gnh, gnl;
            split16(ux, hux, lux);
            split16(uy, huy, luy);
            split16(uz, huz, luz);
            split16(gn, gnh, gnl);
            half8 k0, k1;
            k0[0] = hux; k0[1] = huy; k0[2] = huz;
            k0[3] = hux; k0[4] = huy; k0[5] = huz;
            k0[6] = lux; k0[7] = luy;
            k1[0] = luz; k1[1] = gnh; k1[2] = gnl;
            k1[3] = (_Float16)0.0f; k1[4] = (_Float16)0.0f; k1[5] = (_Float16)0.0f;
            k1[6] = (_Float16)0.0f; k1[7] = (_Float16)0.0f;
            const int t = nl >> 5, r = nl & 31;
            aT[t * 64 + r]      = k0;
            aT[t * 64 + 32 + r] = k1;
        }
    }

    // ---- B-fragments (pred side), constant across tiles ----
    float pR[9];
#pragma unroll
    for (int i = 0; i < 9; ++i) pR[i] = pred_R[b * 9 + i];
    const float ptx = pred_t[b * 3 + 0];
    const float pty = pred_t[b * 3 + 1];
    const float ptz = pred_t[b * 3 + 2];

    half8 bf[FRAGS];
    float pn[FRAGS];
    const int kh = ln >> 5;
#pragma unroll
    for (int f = 0; f < FRAGS; ++f) {
        const int predl = pg * PREDS_PER_BLK + wv * 128 + f * 32 + (ln & 31);
        const float mx = mp[predl * 3 + 0];
        const float my = mp[predl * 3 + 1];
        const float mz = mp[predl * 3 + 2];
        const float px = fmaf(pR[0], mx, fmaf(pR[1], my, fmaf(pR[2], mz, ptx)));
        const float py = fmaf(pR[3], mx, fmaf(pR[4], my, fmaf(pR[5], mz, pty)));
        const float pz = fmaf(pR[6], mx, fmaf(pR[7], my, fmaf(pR[8], mz, ptz)));
        pn[f] = fmaf(px, px, fmaf(py, py, pz * pz));
        _Float16 hpx, lpx, hpy, lpy, hpz, lpz;
        split16(px, hpx, lpx);
        split16(py, hpy, lpy);
        split16(pz, hpz, lpz);
        half8 v;
        if (kh == 0) {
            v[0] = hpx; v[1] = hpy; v[2] = hpz;
            v[3] = lpx; v[4] = lpy; v[5] = lpz;
            v[6] = hpx; v[7] = hpy;
        } else {
            v[0] = hpz; v[1] = (_Float16)1.0f; v[2] = (_Float16)1.0f;
            v[3] = (_Float16)0.0f; v[4] = (_Float16)0.0f;
            v[5] = (_Float16)0.0f; v[6] = (_Float16)0.0f;
            v[7] = (_Float16)0.0f;
        }
        bf[f] = v;
    }

    __syncthreads();

    // ---- MFMA loop over 16 gt tiles (2+2 MFMA groups, low reg pressure) ----
    f32x16 zc;
#pragma unroll
    for (int i = 0; i < 16; ++i) zc[i] = 0.0f;

    float best[FRAGS][8];
#pragma unroll
    for (int f = 0; f < FRAGS; ++f)
#pragma unroll
        for (int j = 0; j < 8; ++j) best[f][j] = FLT_MAX;

    half8 a_cur = aT[ln];
    for (int t = 0; t < NT; ++t) {
        const half8 a_nxt = (t + 1 < NT) ? aT[(t + 1) * 64 + ln] : a_cur;
        {
            const f32x16 d0 = __builtin_amdgcn_mfma_f32_32x32x16_f16(a_cur, bf[0], zc, 0, 0, 0);
            const f32x16 d1 = __builtin_amdgcn_mfma_f32_32x32x16_f16(a_cur, bf[1], zc, 0, 0, 0);
#pragma unroll
            for (int j = 0; j < 8; ++j) {
                best[0][j] = fminf(best[0][j], fminf(d0[2 * j], d0[2 * j + 1]));
                best[1][j] = fminf(best[1][j], fminf(d1[2 * j], d1[2 * j + 1]));
            }
        }
        {
            const f32x16 d2 = __builtin_amdgcn_mfma_f32_32x32x16_f16(a_cur, bf[2], zc, 0, 0, 0);
            const f32x16 d3 = __builtin_amdgcn_mfma_f32_32x32x16_f16(a_cur, bf[3], zc, 0, 0, 0);
#pragma unroll
            for (int j = 0; j < 8; ++j) {
                best[2][j] = fminf(best[2][j], fminf(d2[2 * j], d2[2 * j + 1]));
                best[3][j] = fminf(best[3][j], fminf(d3[2 * j], d3[2 * j + 1]));
            }
        }
        a_cur = a_nxt;
    }

    // ---- epilogue: fold 8 regs, merge lane halves, add pn, store ----
#pragma unroll
    for (int f = 0; f < FRAGS; ++f) {
        float r = fminf(fminf(fminf(best[f][0], best[f][1]), fminf(best[f][2], best[f][3])),
                        fminf(fminf(best[f][4], best[f][5]), fminf(best[f][6], best[f][7])));
        r = fminf(r, __shfl_xor(r, 32, 64));
        const float d2v = fmaxf(pn[f] + r, 0.0f);
        if (ln < 32) {
            const int predl = pg * PREDS_PER_BLK + wv * 128 + f * 32 + ln;
            pmin[gtq * NPRED + b * MPTS + predl] = d2v;
        }
    }
}

// Finish: per pred point min over the 8 partials -> sqrt -> block sum ->
// atomicAdd of the scaled partial into out[0] (zeroed by adds_mfma).
__global__ __launch_bounds__(512) void adds_finish(
    const float* __restrict__ pmin, float* __restrict__ out)
{
    __shared__ float wsum[8];
    const int tid = threadIdx.x;
    const int g = blockIdx.x * 512 + tid;
    float m0 = FLT_MAX, m1 = FLT_MAX;
#pragma unroll
    for (int q = 0; q < GTQ; q += 2) {
        m0 = fminf(m0, pmin[(q + 0) * NPRED + g]);
        m1 = fminf(m1, pmin[(q + 1) * NPRED + g]);
    }
    float s = sqrtf(fminf(m0, m1));
#pragma unroll
    for (int off = 32; off > 0; off >>= 1) s += __shfl_down(s, off, 64);
    if ((tid & 63) == 0) wsum[tid >> 6] = s;
    __syncthreads();
    if (tid == 0) {
        float t = 0.0f;
#pragma unroll
        for (int w = 0; w < 8; ++w) t += wsum[w];
        atomicAdd(out, t * (1.0f / (float)NPRED));
    }
}

extern "C" void kernel_launch(void* const* d_in, const int* in_sizes, int n_in,
                              void* d_out, int out_size, void* d_ws, size_t ws_size,
                              hipStream_t stream) {
    const float* pred_R = (const float*)d_in[0];
    const float* pred_t = (const float*)d_in[1];
    const float* gt_R   = (const float*)d_in[2];
    const float* gt_t   = (const float*)d_in[3];
    const float* mp     = (const float*)d_in[4];
    float* out = (float*)d_out;
    float* pmin = (float*)d_ws;                 // 8*64K*4 = 2 MB

    // grid: b(16) x pred-group(8) x gtq(8) = 1024 blocks (4 blocks/CU)
    adds_mfma<<<dim3(NB * PGRP * GTQ), dim3(BLK), 0, stream>>>(
        pred_R, pred_t, gt_R, gt_t, mp, pmin, out);
    adds_finish<<<dim3(NPRED / 512), dim3(512), 0, stream>>>(pmin, out);
}